// Round 4
// baseline (14749.590 us; speedup 1.0000x reference)
//
#include <hip/hip_runtime.h>
#include <hip/hip_bf16.h>
#include <math.h>

typedef __hip_bfloat16 bf16;

// Problem constants
constexpr int CB   = 32;    // batch
constexpr int CN   = 256;   // tokens
constexpr int CD   = 384;   // model dim (incl. time)
constexpr int CDS  = 383;   // space dim
constexpr int CH   = 6;     // heads
constexpr int CHC  = 64;    // head channels (incl. time)
constexpr int CHCS = 63;    // head space channels
constexpr int CL   = 12;    // layers
constexpr int CMH  = 1536;  // mlp hidden (incl. time)
constexpr int CMHS = 1535;
constexpr int CROWS = CB * CN;        // 8192
constexpr int CKP  = 784;             // patch vector length (14*14*4)
constexpr int CQN  = CH * CHCS;       // 378 (packed qkv out cols)

static inline int cdiv(int a, int b){ return (a + b - 1) / b; }

// Dual-dtype input load: isb=1 -> bf16, isb=0 -> fp32. Wave-uniform isb.
__device__ __forceinline__ float ldin(const void* p, size_t i, int isb) {
    if (isb) return __bfloat162float(((const bf16*)p)[i]);
    return ((const float*)p)[i];
}

// ---------------------------------------------------------------------------
// Dtype detector: scan first 4096 u16 of x. bf16 data -> ~100% sane exponents;
// fp32 data read as u16 -> ~59% (low halves are uniform mantissa bits).
// ---------------------------------------------------------------------------
__global__ __launch_bounds__(256)
void detect_kernel(const void* __restrict__ x, int* __restrict__ flag) {
    __shared__ int red[256];
    const unsigned short* u = (const unsigned short*)x;
    int cnt = 0;
    for (int i = threadIdx.x; i < 4096; i += 256) {
        unsigned short v = u[i];
        int e = (v >> 7) & 0xFF;
        cnt += (v == 0 || (e >= 96 && e <= 142)) ? 1 : 0;
    }
    red[threadIdx.x] = cnt;
    __syncthreads();
    for (int off = 128; off > 0; off >>= 1) {
        if (threadIdx.x < off) red[threadIdx.x] += red[threadIdx.x + off];
        __syncthreads();
    }
    if (threadIdx.x == 0) flag[0] = (red[0] >= 3482) ? 1 : 0;   // >=85% sane
}

// ---------------------------------------------------------------------------
// Patchify: x[B,3,224,224] -> patches[8192,784] fp32 with add_time per px
// patch vector layout: (pi*14+pj)*4 + c, c0=t, c1..3=rgb
// ---------------------------------------------------------------------------
__global__ __launch_bounds__(256)
void patchify_kernel(const void* __restrict__ x, float* __restrict__ patches,
                     const int* __restrict__ flg) {
    int isb = flg[0];
    int idx = blockIdx.x * 256 + threadIdx.x;      // b*224*224 + row*224 + col
    if (idx >= CB * 224 * 224) return;
    int col = idx % 224;
    int t   = idx / 224;
    int row = t % 224;
    int b   = t / 224;
    size_t base = ((size_t)b * 3) * 224 * 224 + (size_t)row * 224 + col;
    float r  = ldin(x, base, isb);
    float g  = ldin(x, base + 224 * 224, isb);
    float bl = ldin(x, base + 2 * 224 * 224, isb);
    float tt = sqrtf(1.0f + r * r + g * g + bl * bl);
    int gi = row / 14, pi = row % 14, gj = col / 14, pj = col % 14;
    int p = gi * 16 + gj;
    float* dp = patches + ((size_t)(b * CN + p)) * CKP + (pi * 14 + pj) * 4;
    *(float4*)dp = make_float4(tt, r, g, bl);
}

// ---------------------------------------------------------------------------
// Generic GEMM: C[M,N] = A[M,K] @ W[K,N] + bias[N]
// A fp32 (lda=K), W dual-dtype, C fp32 (ldc=N). M multiple of 64, K multiple
// of 16, N arbitrary (guarded). wmode=0: W row-major [K,N] at element offset
// woff. wmode=1: qkv layout, W[h,k,e] with col c=h*63+e.
// grid = (cdiv(N,64), M/64), 256 threads.
// ---------------------------------------------------------------------------
__global__ __launch_bounds__(256)
void gemm_kernel(const float* __restrict__ A, const void* __restrict__ W,
                 size_t woff, const void* __restrict__ bias, size_t boff,
                 float* __restrict__ C, int N, int K, int wmode,
                 const int* __restrict__ flg) {
    int isb = flg[0];
    __shared__ float As[16][68];
    __shared__ float Ws[16][68];
    int tid = threadIdx.x;
    int tm = tid / 16;            // 0..15
    int tn = tid % 16;            // 0..15
    int bm = blockIdx.y * 64;
    int bn = blockIdx.x * 64;
    float acc[4][4] = {};
    for (int k0 = 0; k0 < K; k0 += 16) {
        {   // A tile 64x16: thread -> row=tid/4, 4 consecutive k
            int row = tid >> 2;
            int kc  = (tid & 3) << 2;
            const float* ap = A + (size_t)(bm + row) * K + k0 + kc;
            float4 av = *(const float4*)ap;
            As[kc + 0][row] = av.x; As[kc + 1][row] = av.y;
            As[kc + 2][row] = av.z; As[kc + 3][row] = av.w;
        }
        {   // W tile 16x64: thread -> kr=tid/16, 4 consecutive n
            int kr = tid >> 4;
            int nc = (tid & 15) << 2;
            int krow = k0 + kr;
            #pragma unroll
            for (int i = 0; i < 4; i++) {
                int cidx = bn + nc + i;
                float wv = 0.0f;
                if (cidx < N) {
                    size_t off = wmode
                        ? ((size_t)(cidx / 63) * CD + krow) * 63 + (cidx % 63)
                        : (size_t)krow * N + cidx;
                    wv = ldin(W, woff + off, isb);
                }
                Ws[kr][nc + i] = wv;
            }
        }
        __syncthreads();
        #pragma unroll
        for (int kk = 0; kk < 16; kk++) {
            float4 a4 = *(const float4*)&As[kk][tm * 4];
            float4 w4 = *(const float4*)&Ws[kk][tn * 4];
            float av[4] = {a4.x, a4.y, a4.z, a4.w};
            float wv[4] = {w4.x, w4.y, w4.z, w4.w};
            #pragma unroll
            for (int i = 0; i < 4; i++)
                #pragma unroll
                for (int j = 0; j < 4; j++)
                    acc[i][j] = fmaf(av[i], wv[j], acc[i][j]);
        }
        __syncthreads();
    }
    #pragma unroll
    for (int i = 0; i < 4; i++) {
        int r = bm + tm * 4 + i;
        #pragma unroll
        for (int j = 0; j < 4; j++) {
            int c = bn + tn * 4 + j;
            if (c < N) {
                C[(size_t)r * N + c] = acc[i][j] + ldin(bias, boff + c, isb);
            }
        }
    }
}

// ---------------------------------------------------------------------------
// add_time rows: dst[row,0] = sqrt(1+||s||^2), dst[row,1+j] = s_j
// optional fused tanh-GELU on s first. src [M,NS], dst [M,NS+1].
// ---------------------------------------------------------------------------
__global__ __launch_bounds__(256)
void add_time_rows_kernel(const float* __restrict__ src, float* __restrict__ dst,
                          int NS, int do_gelu) {
    int row = blockIdx.x;
    int tid = threadIdx.x;
    __shared__ float buf[1536];
    __shared__ float red[256];
    const float* sr = src + (size_t)row * NS;
    float ss = 0.0f;
    for (int j = tid; j < NS; j += 256) {
        float vv = sr[j];
        if (do_gelu) {
            float x3 = vv * vv * vv;
            vv = 0.5f * vv * (1.0f + tanhf(0.7978845608028654f * (vv + 0.044715f * x3)));
        }
        buf[j] = vv;
        ss += vv * vv;
    }
    red[tid] = ss;
    __syncthreads();
    for (int off = 128; off > 0; off >>= 1) {
        if (tid < off) red[tid] += red[tid + off];
        __syncthreads();
    }
    float t = sqrtf(1.0f + red[0]);
    float* dr = dst + (size_t)row * (NS + 1);
    if (tid == 0) dr[0] = t;
    for (int j = tid; j < NS; j += 256) dr[1 + j] = buf[j];
}

// ---------------------------------------------------------------------------
// Lorentz layernorm: x[M,384] -> out[M,384], g/b dual-dtype at goff/boff.
// ---------------------------------------------------------------------------
__global__ __launch_bounds__(256)
void llayernorm_kernel(const float* __restrict__ x, const void* __restrict__ g,
                       size_t goff, const void* __restrict__ b, size_t boff,
                       float* __restrict__ out, const int* __restrict__ flg) {
    int isb = flg[0];
    int row = blockIdx.x;
    int tid = threadIdx.x;
    const float* xr = x + (size_t)row * CD;
    __shared__ float red[256];
    __shared__ float red2[256];
    int j0 = tid, j1 = tid + 256;              // indices into space (0..382)
    float v0 = xr[1 + j0];
    float v1 = (j1 < CDS) ? xr[1 + j1] : 0.0f;
    red[tid]  = v0 + v1;
    red2[tid] = v0 * v0 + v1 * v1;
    __syncthreads();
    for (int off = 128; off > 0; off >>= 1) {
        if (tid < off) { red[tid] += red[tid + off]; red2[tid] += red2[tid + off]; }
        __syncthreads();
    }
    float mu  = red[0] * (1.0f / 383.0f);
    float var = red2[0] * (1.0f / 383.0f) - mu * mu;
    __syncthreads();
    float rstd = rsqrtf(var + 1e-5f);
    float y0 = (v0 - mu) * rstd * ldin(g, goff + j0, isb) + ldin(b, boff + j0, isb);
    float y1 = 0.0f;
    if (j1 < CDS) y1 = (v1 - mu) * rstd * ldin(g, goff + j1, isb) + ldin(b, boff + j1, isb);
    red[tid] = y0 * y0 + y1 * y1;
    __syncthreads();
    for (int off = 128; off > 0; off >>= 1) {
        if (tid < off) red[tid] += red[tid + off];
        __syncthreads();
    }
    float t = sqrtf(1.0f + red[0]);
    float* orow = out + (size_t)row * CD;
    orow[1 + j0] = y0;
    if (j1 < CDS) orow[1 + j1] = y1;
    if (tid == 0) orow[0] = t;
}

// ---------------------------------------------------------------------------
// lresnet: out = lnormalize(x + scale*y), x/y/out [M,384] fp32 (in-place safe)
// ---------------------------------------------------------------------------
__global__ __launch_bounds__(256)
void lresnet_kernel(const float* __restrict__ x, const float* __restrict__ y,
                    float scale, float* __restrict__ out) {
    int row = blockIdx.x;
    int tid = threadIdx.x;
    const float* xr = x + (size_t)row * CD;
    const float* yr = y + (size_t)row * CD;
    __shared__ float red[256];
    float z0 = xr[tid] + scale * yr[tid];
    float z1 = 0.0f;
    float c = (tid == 0) ? z0 * z0 : -z0 * z0;
    if (tid < 128) { z1 = xr[256 + tid] + scale * yr[256 + tid]; c -= z1 * z1; }
    red[tid] = c;
    __syncthreads();
    for (int off = 128; off > 0; off >>= 1) {
        if (tid < off) red[tid] += red[tid + off];
        __syncthreads();
    }
    float rd = 1.0f / sqrtf(fmaxf(red[0], 1e-8f));
    float* orow = out + (size_t)row * CD;
    orow[tid] = z0 * rd;
    if (tid < 128) orow[256 + tid] = z1 * rd;
}

// lresnet vs broadcast dual-dtype pe (scale = 1)
__global__ __launch_bounds__(256)
void lresnet_pe_kernel(const float* __restrict__ x, const void* __restrict__ pe,
                       float* __restrict__ out, const int* __restrict__ flg) {
    int isb = flg[0];
    int row = blockIdx.x;
    int tid = threadIdx.x;
    const float* xr = x + (size_t)row * CD;
    size_t pb = (size_t)(row & (CN - 1)) * CD;
    __shared__ float red[256];
    float z0 = xr[tid] + ldin(pe, pb + tid, isb);
    float z1 = 0.0f;
    float c = (tid == 0) ? z0 * z0 : -z0 * z0;
    if (tid < 128) { z1 = xr[256 + tid] + ldin(pe, pb + 256 + tid, isb); c -= z1 * z1; }
    red[tid] = c;
    __syncthreads();
    for (int off = 128; off > 0; off >>= 1) {
        if (tid < off) red[tid] += red[tid + off];
        __syncthreads();
    }
    float rd = 1.0f / sqrtf(fmaxf(red[0], 1e-8f));
    float* orow = out + (size_t)row * CD;
    orow[tid] = z0 * rd;
    if (tid < 128) orow[256 + tid] = z1 * rd;
}

// ---------------------------------------------------------------------------
// qkv finish: src[8192,378] (bias already added in GEMM) -> dst[B,H,N,64]
// with add_time. grid (8192, 6), 64 threads.
// ---------------------------------------------------------------------------
__global__ __launch_bounds__(64)
void qkv_finish_kernel(const float* __restrict__ src, float* __restrict__ dst) {
    int row = blockIdx.x;              // b*256+n
    int h   = blockIdx.y;
    int e   = threadIdx.x;             // 0..63
    float y = (e < CHCS) ? src[(size_t)row * CQN + h * CHCS + e] : 0.0f;
    float ss = y * y;
    #pragma unroll
    for (int off = 32; off > 0; off >>= 1) ss += __shfl_down(ss, off);
    float t = sqrtf(1.0f + __shfl(ss, 0));
    int b = row >> 8, n = row & 255;
    float* dr = dst + (((size_t)(b * CH + h)) * CN + n) * CHC;
    if (e < CHCS) dr[1 + e] = y;
    if (e == 0)   dr[0] = t;
}

// ---------------------------------------------------------------------------
// Fused Lorentz attention for one (b,h,n): scores -> softmax -> PV ->
// lnormalize -> write concat layout attcat[b,n,h*64+c]. grid (256, B*H).
// ---------------------------------------------------------------------------
__global__ __launch_bounds__(256)
void attn_kernel(const float* __restrict__ q, const float* __restrict__ k,
                 const float* __restrict__ v, float* __restrict__ attcat) {
    int n  = blockIdx.x;
    int bh = blockIdx.y;               // b*H + h
    int h  = bh % CH;
    int b  = bh / CH;
    int tid = threadIdx.x;
    __shared__ float qs[CHC];
    __shared__ float sc[CN];
    __shared__ float red[CN];
    const float* qrow = q + ((size_t)bh * CN + n) * CHC;
    if (tid < CHC) qs[tid] = qrow[tid];
    __syncthreads();
    // scores: thread m
    const float* krow = k + ((size_t)bh * CN + tid) * CHC;
    float inner = -qs[0] * krow[0];
    #pragma unroll
    for (int c = 1; c < CHC; c++) inner += qs[c] * krow[c];
    float s = (2.0f + 2.0f * inner) * 0.125f;   // (2/K + 2*inner)/sqrt(64)
    sc[tid] = s;
    red[tid] = s;
    __syncthreads();
    for (int off = 128; off > 0; off >>= 1) {
        if (tid < off) red[tid] = fmaxf(red[tid], red[tid + off]);
        __syncthreads();
    }
    float mx = red[0];
    __syncthreads();
    float e = __expf(s - mx);
    sc[tid] = e;
    red[tid] = e;
    __syncthreads();
    for (int off = 128; off > 0; off >>= 1) {
        if (tid < off) red[tid] += red[tid + off];
        __syncthreads();
    }
    float rsum = 1.0f / red[0];
    __syncthreads();
    // PV + lnormalize: lanes 0..63 of wave 0 each own channel c
    if (tid < CHC) {
        int c = tid;
        const float* vb = v + (size_t)bh * CN * CHC + c;
        float acc = 0.0f;
        #pragma unroll 4
        for (int m = 0; m < CN; m++) acc += sc[m] * vb[(size_t)m * CHC];
        acc *= rsum;
        float val = (c == 0) ? acc * acc : -acc * acc;   // -ldot partial
        #pragma unroll
        for (int off = 32; off > 0; off >>= 1) val += __shfl_down(val, off);
        float nld = __shfl(val, 0);
        float d = sqrtf(fmaxf(nld, 1e-8f));
        attcat[((size_t)b * CN + n) * CD + h * CHC + c] = acc / d;
    }
}

// ---------------------------------------------------------------------------
// mean-pool over tokens + lnormalize -> emb[32,384]
// ---------------------------------------------------------------------------
__global__ __launch_bounds__(256)
void meanpool_kernel(const float* __restrict__ hbuf, float* __restrict__ emb) {
    int b = blockIdx.x;
    int tid = threadIdx.x;
    const float* hb = hbuf + (size_t)b * CN * CD;
    float s0 = 0.0f, s1 = 0.0f;
    for (int n = 0; n < CN; n++) {
        s0 += hb[(size_t)n * CD + tid];
        if (tid < 128) s1 += hb[(size_t)n * CD + 256 + tid];
    }
    s0 *= (1.0f / 256.0f);
    s1 *= (1.0f / 256.0f);
    __shared__ float red[256];
    float c = (tid == 0) ? s0 * s0 : -s0 * s0;
    if (tid < 128) c -= s1 * s1;
    red[tid] = c;
    __syncthreads();
    for (int off = 128; off > 0; off >>= 1) {
        if (tid < off) red[tid] += red[tid + off];
        __syncthreads();
    }
    float rd = 1.0f / sqrtf(fmaxf(red[0], 1e-8f));
    emb[(size_t)b * CD + tid] = s0 * rd;
    if (tid < 128) emb[(size_t)b * CD + 256 + tid] = s1 * rd;
}

// ---------------------------------------------------------------------------
// MLR head precompute: per class wt, beta, cosh(a). Dual-dtype inputs.
// ---------------------------------------------------------------------------
__global__ __launch_bounds__(256)
void head_pre_kernel(const void* __restrict__ mlra, const void* __restrict__ mlrz,
                     float* __restrict__ wt, float* __restrict__ beta,
                     float* __restrict__ cha, const int* __restrict__ flg) {
    int isb = flg[0];
    int c = blockIdx.x * 256 + threadIdx.x;
    if (c >= 1000) return;
    float S = 0.0f;
    for (int j = 0; j < CDS; j++) {
        float zz = ldin(mlrz, (size_t)c * CDS + j, isb);
        S += zz * zz;
    }
    float a  = ldin(mlra, c, isb);
    float sh = sinhf(a), ch = coshf(a);
    float zn = sqrtf(S + 1e-8f);
    float w  = sh * zn;
    wt[c]  = w;
    cha[c] = ch;
    beta[c] = sqrtf(fmaxf(ch * ch * S - w * w, 1e-8f));
}

// logits[b,c] = beta * arcsinh(alpha/beta); grid (32, 4), 256 thr.
// OUTPUT DTYPE MATCHES INPUT DTYPE: fp32 when flag=0 (expected), bf16 when 1.
__global__ __launch_bounds__(256)
void head_logits_kernel(const float* __restrict__ emb, const void* __restrict__ mlrz,
                        const float* __restrict__ wt, const float* __restrict__ beta,
                        const float* __restrict__ cha, void* __restrict__ out,
                        const int* __restrict__ flg) {
    int isb = flg[0];
    int b = blockIdx.x;
    int c = blockIdx.y * 256 + threadIdx.x;
    __shared__ float es[CD];
    for (int j = threadIdx.x; j < CD; j += 256) es[j] = emb[(size_t)b * CD + j];
    __syncthreads();
    if (c < 1000) {
        float dotv = 0.0f;
        for (int j = 0; j < CDS; j++)
            dotv += es[1 + j] * ldin(mlrz, (size_t)c * CDS + j, isb);
        float alpha = -es[0] * wt[c] + cha[c] * dotv;
        float be = beta[c];
        float lg = be * asinhf(alpha / be);
        if (isb) ((bf16*)out)[(size_t)b * 1000 + c] = __float2bfloat16(lg);
        else     ((float*)out)[(size_t)b * 1000 + c] = lg;
    }
}

// ---------------------------------------------------------------------------
// Orchestration.
// Workspace (floats), FH = 8192*384 = 3,145,728:
//   hbuf   @ 0       (FH)     residual stream
//   xln    @ FH      (FH)     LN output (KEPT ALIVE through attention!)
//   big1   @ 2*FH    (4*FH)   gemm outs up to 8192x1535 / patches
//   big2   @ 6*FH    (4*FH)   q,k,v (3*FH) + attcat (FH) during attention;
//                             attn-block add_time out reuses qb (6FH);
//                             mlp hidden 8192x1536 (exactly 4*FH)
//   emb    @ 10*FH   (12288)
//   wt/beta/cha      (3000)
//   flag             (1 int)
// Total ~125.9 MB.
// ---------------------------------------------------------------------------
extern "C" void kernel_launch(void* const* d_in, const int* in_sizes, int n_in,
                              void* d_out, int out_size, void* d_ws, size_t ws_size,
                              hipStream_t stream) {
    const void* x      = d_in[0];
    const void* patchW = d_in[1];
    const void* patchB = d_in[2];
    const void* pe     = d_in[3];
    const void* ln1g   = d_in[4];
    const void* ln1b   = d_in[5];
    const void* ln2g   = d_in[6];
    const void* ln2b   = d_in[7];
    const void* Wq     = d_in[8];
    const void* bq     = d_in[9];
    const void* Wk     = d_in[10];
    const void* bk     = d_in[11];
    const void* Wv     = d_in[12];
    const void* bv     = d_in[13];
    const void* Wo     = d_in[14];
    const void* bo     = d_in[15];
    const void* W1     = d_in[16];
    const void* b1     = d_in[17];
    const void* W2     = d_in[18];
    const void* b2     = d_in[19];
    const void* mlra   = d_in[20];
    const void* mlrz   = d_in[21];

    float* ws = (float*)d_ws;
    const size_t FH = (size_t)CROWS * CD;
    float* hbuf   = ws;
    float* xln    = ws + FH;
    float* big1   = ws + 2 * FH;
    float* big2   = ws + 6 * FH;
    float* qb     = big2;
    float* kb     = big2 + FH;
    float* vb     = big2 + 2 * FH;
    float* attcat = big2 + 3 * FH;   // separate region: xln must stay alive
    float* attout = big2;            // add_time(Wo out) -> reuse qb (dead)
    float* emb    = ws + 10 * FH;
    float* wt     = emb + (size_t)CB * CD;
    float* beta   = wt + 1000;
    float* cha    = beta + 1000;
    int*   flag   = (int*)(cha + 1000);

    const size_t WQKV = (size_t)CH * CD * CHCS;   // per-layer qkv weight elems

    // dtype detection (must run first; everything reads flag from device)
    detect_kernel<<<1, 256, 0, stream>>>(x, flag);

    // patch embed
    patchify_kernel<<<cdiv(CB * 224 * 224, 256), 256, 0, stream>>>(x, big1, flag);
    gemm_kernel<<<dim3(cdiv(CDS, 64), CROWS / 64), 256, 0, stream>>>(
        big1, patchW, 0, patchB, 0, big2, CDS, CKP, 0, flag);
    add_time_rows_kernel<<<CROWS, 256, 0, stream>>>(big2, xln, CDS, 0);
    lresnet_pe_kernel<<<CROWS, 256, 0, stream>>>(xln, pe, hbuf, flag);

    for (int l = 0; l < CL; l++) {
        // --- attention block ---
        // Reference rebinds h = llayernorm(h,...) BEFORE attention, so the
        // attention residual base is the LN1 OUTPUT (xln), not hbuf.
        llayernorm_kernel<<<CROWS, 256, 0, stream>>>(
            hbuf, ln1g, (size_t)l * CDS, ln1b, (size_t)l * CDS, xln, flag);
        gemm_kernel<<<dim3(cdiv(CQN, 64), CROWS / 64), 256, 0, stream>>>(
            xln, Wq, (size_t)l * WQKV, bq, (size_t)l * CQN, big1, CQN, CD, 1, flag);
        qkv_finish_kernel<<<dim3(CROWS, CH), 64, 0, stream>>>(big1, qb);
        gemm_kernel<<<dim3(cdiv(CQN, 64), CROWS / 64), 256, 0, stream>>>(
            xln, Wk, (size_t)l * WQKV, bk, (size_t)l * CQN, big1, CQN, CD, 1, flag);
        qkv_finish_kernel<<<dim3(CROWS, CH), 64, 0, stream>>>(big1, kb);
        gemm_kernel<<<dim3(cdiv(CQN, 64), CROWS / 64), 256, 0, stream>>>(
            xln, Wv, (size_t)l * WQKV, bv, (size_t)l * CQN, big1, CQN, CD, 1, flag);
        qkv_finish_kernel<<<dim3(CROWS, CH), 64, 0, stream>>>(big1, vb);
        attn_kernel<<<dim3(CN, CB * CH), 256, 0, stream>>>(qb, kb, vb, attcat);
        gemm_kernel<<<dim3(cdiv(CDS, 64), CROWS / 64), 256, 0, stream>>>(
            attcat, Wo, (size_t)l * CD * CDS, bo, (size_t)l * CDS, big1, CDS, CD, 0, flag);
        add_time_rows_kernel<<<CROWS, 256, 0, stream>>>(big1, attout, CDS, 0);
        lresnet_kernel<<<CROWS, 256, 0, stream>>>(xln, attout, 27.5f, hbuf);
        // --- mlp block (residual base here IS hbuf, per reference) ---
        llayernorm_kernel<<<CROWS, 256, 0, stream>>>(
            hbuf, ln2g, (size_t)l * CDS, ln2b, (size_t)l * CDS, xln, flag);
        gemm_kernel<<<dim3(cdiv(CMHS, 64), CROWS / 64), 256, 0, stream>>>(
            xln, W1, (size_t)l * CD * CMHS, b1, (size_t)l * CMHS, big1, CMHS, CD, 0, flag);
        add_time_rows_kernel<<<CROWS, 256, 0, stream>>>(big1, big2, CMHS, 1);
        gemm_kernel<<<dim3(cdiv(CDS, 64), CROWS / 64), 256, 0, stream>>>(
            big2, W2, (size_t)l * CMH * CDS, b2, (size_t)l * CDS, big1, CDS, CMH, 0, flag);
        add_time_rows_kernel<<<CROWS, 256, 0, stream>>>(big1, xln, CDS, 0);
        lresnet_kernel<<<CROWS, 256, 0, stream>>>(hbuf, xln, 27.5f, hbuf);
    }

    // head
    meanpool_kernel<<<CB, 256, 0, stream>>>(hbuf, emb);
    head_pre_kernel<<<4, 256, 0, stream>>>(mlra, mlrz, wt, beta, cha, flag);
    head_logits_kernel<<<dim3(CB, 4), 256, 0, stream>>>(emb, mlrz, wt, beta, cha, d_out, flag);
}

// Round 5
// 7327.000 us; speedup vs baseline: 2.0130x; 2.0130x over previous
//
#include <hip/hip_runtime.h>
#include <hip/hip_bf16.h>
#include <math.h>

typedef __hip_bfloat16 bf16;

// Problem constants
constexpr int CB   = 32;    // batch
constexpr int CN   = 256;   // tokens
constexpr int CD   = 384;   // model dim (incl. time)
constexpr int CDS  = 383;   // space dim
constexpr int CH   = 6;     // heads
constexpr int CHC  = 64;    // head channels (incl. time)
constexpr int CHCS = 63;    // head space channels
constexpr int CL   = 12;    // layers
constexpr int CMH  = 1536;  // mlp hidden (incl. time)
constexpr int CMHS = 1535;
constexpr int CROWS = CB * CN;        // 8192
constexpr int CKP  = 784;             // patch vector length (14*14*4)
constexpr int CQN  = CH * CHCS;       // 378 (packed qkv out cols)

static inline int cdiv(int a, int b){ return (a + b - 1) / b; }

// MFMA frag types (per cdna_hip_programming.md §3 snippet: short8 / float4)
typedef short bf8_t __attribute__((ext_vector_type(8)));
typedef float f4_t  __attribute__((ext_vector_type(4)));

// fp32 -> bf16 (RNE) as raw ushort
__device__ __forceinline__ unsigned short f2bf(float f) {
    union { float f; unsigned u; } x; x.f = f;
    unsigned r = x.u + 0x7FFFu + ((x.u >> 16) & 1u);
    return (unsigned short)(r >> 16);
}
__device__ __forceinline__ float bf2f(unsigned short h) {
    union { unsigned u; float f; } x; x.u = ((unsigned)h) << 16;
    return x.f;
}

// Dual-dtype input load: isb=1 -> bf16, isb=0 -> fp32. Wave-uniform isb.
__device__ __forceinline__ float ldin(const void* p, size_t i, int isb) {
    if (isb) return __bfloat162float(((const bf16*)p)[i]);
    return ((const float*)p)[i];
}

// ---------------------------------------------------------------------------
// Dtype detector (inputs fp32 expected; bf16 fallback).
// ---------------------------------------------------------------------------
__global__ __launch_bounds__(256)
void detect_kernel(const void* __restrict__ x, int* __restrict__ flag) {
    __shared__ int red[256];
    const unsigned short* u = (const unsigned short*)x;
    int cnt = 0;
    for (int i = threadIdx.x; i < 4096; i += 256) {
        unsigned short v = u[i];
        int e = (v >> 7) & 0xFF;
        cnt += (v == 0 || (e >= 96 && e <= 142)) ? 1 : 0;
    }
    red[threadIdx.x] = cnt;
    __syncthreads();
    for (int off = 128; off > 0; off >>= 1) {
        if (threadIdx.x < off) red[threadIdx.x] += red[threadIdx.x + off];
        __syncthreads();
    }
    if (threadIdx.x == 0) flag[0] = (red[0] >= 3482) ? 1 : 0;
}

// ---------------------------------------------------------------------------
// Patchify: x[B,3,224,224] -> patches[8192,784] fp32 with add_time per px
// ---------------------------------------------------------------------------
__global__ __launch_bounds__(256)
void patchify_kernel(const void* __restrict__ x, float* __restrict__ patches,
                     const int* __restrict__ flg) {
    int isb = flg[0];
    int idx = blockIdx.x * 256 + threadIdx.x;
    if (idx >= CB * 224 * 224) return;
    int col = idx % 224;
    int t   = idx / 224;
    int row = t % 224;
    int b   = t / 224;
    size_t base = ((size_t)b * 3) * 224 * 224 + (size_t)row * 224 + col;
    float r  = ldin(x, base, isb);
    float g  = ldin(x, base + 224 * 224, isb);
    float bl = ldin(x, base + 2 * 224 * 224, isb);
    float tt = sqrtf(1.0f + r * r + g * g + bl * bl);
    int gi = row / 14, pi = row % 14, gj = col / 14, pj = col % 14;
    int p = gi * 16 + gj;
    float* dp = patches + ((size_t)(b * CN + p)) * CKP + (pi * 14 + pj) * 4;
    *(float4*)dp = make_float4(tt, r, g, bl);
}

// ---------------------------------------------------------------------------
// MFMA GEMM: C[M,N] = A[M,K] @ W[K,N] + bias[N].
// A fp32 (lda=K, K mult of 8), W dual-dtype (wmode=0 row-major [K,N] at woff;
// wmode=1 qkv [h,k,e], col=h*63+e), C fp32 ldc=N. Tile 64x64, BK=32,
// mfma_f32_16x16x32_bf16, fp32 accum. grid (cdiv(N,64), M/64), 256 thr.
// LDS is fragment-ordered: frag loads are conflict-free ds_read_b128.
//   A/B operand: lane holds X[nonK = lane&15][k = (lane>>4)*8 + j]
//   C/D: col = lane&15, row = (lane>>4)*4 + reg      [m89/m120 verified]
// ---------------------------------------------------------------------------
__global__ __launch_bounds__(256)
void gemm_kernel(const float* __restrict__ A, const void* __restrict__ W,
                 size_t woff, const void* __restrict__ bias, size_t boff,
                 float* __restrict__ C, int N, int K, int wmode,
                 const int* __restrict__ flg) {
    int isb = flg[0];
    __shared__ __align__(16) short Ablk[4][64][8];   // [mtile][lane][j] 4KB
    __shared__ __align__(16) short Bblk[4][64][8];   // [ntile][lane][j] 4KB
    int tid = threadIdx.x;
    int wave = tid >> 6, lane = tid & 63;
    int bm = blockIdx.y * 64, bn = blockIdx.x * 64;
    int wm = (wave & 1) * 2, wn = (wave >> 1) * 2;   // 2x2 tile quadrant
    f4_t acc[2][2] = {};

    // A staging map: mA = tid>>2 (row), kqA = tid&3 (k-octet)
    int mA = tid >> 2, kqA = tid & 3;
    const float* arow = A + (size_t)(bm + mA) * K;
    // B staging map: nB = bn + (tid&63), kqB = tid>>6 (k-octet)
    int nl = tid & 63;
    int nB = bn + nl;
    int kqB = tid >> 6;
    bool nval = nB < N;
    int ncl = nval ? nB : 0;
    size_t wcol; int wstr;
    if (wmode) { int h = ncl / 63, e = ncl % 63;
                 wcol = woff + (size_t)h * CD * 63 + e; wstr = 63; }
    else       { wcol = woff + ncl; wstr = N; }
    short* awp = &Ablk[mA >> 4][(mA & 15) | (kqA << 4)][0];
    short* bwp = &Bblk[nl >> 4][(nl & 15) | (kqB << 4)][0];

    for (int k0 = 0; k0 < K; k0 += 32) {
        // stage A: 8 floats -> bf16 frag slot (16B ds_write)
        {
            bf8_t av = {0,0,0,0,0,0,0,0};
            int kk = k0 + kqA * 8;
            if (kk < K) {
                float4 f0 = *(const float4*)(arow + kk);
                float4 f1 = *(const float4*)(arow + kk + 4);
                av[0]=(short)f2bf(f0.x); av[1]=(short)f2bf(f0.y);
                av[2]=(short)f2bf(f0.z); av[3]=(short)f2bf(f0.w);
                av[4]=(short)f2bf(f1.x); av[5]=(short)f2bf(f1.y);
                av[6]=(short)f2bf(f1.z); av[7]=(short)f2bf(f1.w);
            }
            *(bf8_t*)awp = av;
        }
        // stage B: 8 k's of column nB (coalesced across lanes per jj)
        {
            bf8_t bv = {0,0,0,0,0,0,0,0};
            #pragma unroll
            for (int jj = 0; jj < 8; jj++) {
                int kr = k0 + kqB * 8 + jj;
                float wv = 0.0f;
                if (nval && kr < K) wv = ldin(W, wcol + (size_t)kr * wstr, isb);
                bv[jj] = (short)f2bf(wv);
            }
            *(bf8_t*)bwp = bv;
        }
        __syncthreads();
        bf8_t a0 = *(const bf8_t*)&Ablk[wm    ][lane][0];
        bf8_t a1 = *(const bf8_t*)&Ablk[wm + 1][lane][0];
        bf8_t b0 = *(const bf8_t*)&Bblk[wn    ][lane][0];
        bf8_t b1 = *(const bf8_t*)&Bblk[wn + 1][lane][0];
        acc[0][0] = __builtin_amdgcn_mfma_f32_16x16x32_bf16(a0, b0, acc[0][0], 0, 0, 0);
        acc[0][1] = __builtin_amdgcn_mfma_f32_16x16x32_bf16(a0, b1, acc[0][1], 0, 0, 0);
        acc[1][0] = __builtin_amdgcn_mfma_f32_16x16x32_bf16(a1, b0, acc[1][0], 0, 0, 0);
        acc[1][1] = __builtin_amdgcn_mfma_f32_16x16x32_bf16(a1, b1, acc[1][1], 0, 0, 0);
        __syncthreads();
    }
    // epilogue
    int colq = lane & 15, rowq = (lane >> 4) * 4;
    #pragma unroll
    for (int ni = 0; ni < 2; ni++) {
        int col = bn + (wn + ni) * 16 + colq;
        if (col >= N) continue;
        float bb = ldin(bias, boff + col, isb);
        #pragma unroll
        for (int mi = 0; mi < 2; mi++) {
            int row = bm + (wm + mi) * 16 + rowq;
            #pragma unroll
            for (int r = 0; r < 4; r++)
                C[(size_t)(row + r) * N + col] = acc[mi][ni][r] + bb;
        }
    }
}

// ---------------------------------------------------------------------------
// add_time rows (+optional GELU). src [M,NS], dst [M,NS+1].
// ---------------------------------------------------------------------------
__global__ __launch_bounds__(256)
void add_time_rows_kernel(const float* __restrict__ src, float* __restrict__ dst,
                          int NS, int do_gelu) {
    int row = blockIdx.x;
    int tid = threadIdx.x;
    __shared__ float buf[1536];
    __shared__ float red[256];
    const float* sr = src + (size_t)row * NS;
    float ss = 0.0f;
    for (int j = tid; j < NS; j += 256) {
        float vv = sr[j];
        if (do_gelu) {
            float x3 = vv * vv * vv;
            vv = 0.5f * vv * (1.0f + tanhf(0.7978845608028654f * (vv + 0.044715f * x3)));
        }
        buf[j] = vv;
        ss += vv * vv;
    }
    red[tid] = ss;
    __syncthreads();
    for (int off = 128; off > 0; off >>= 1) {
        if (tid < off) red[tid] += red[tid + off];
        __syncthreads();
    }
    float t = sqrtf(1.0f + red[0]);
    float* dr = dst + (size_t)row * (NS + 1);
    if (tid == 0) dr[0] = t;
    for (int j = tid; j < NS; j += 256) dr[1 + j] = buf[j];
}

// ---------------------------------------------------------------------------
// Lorentz layernorm: x[M,384] -> out[M,384]
// ---------------------------------------------------------------------------
__global__ __launch_bounds__(256)
void llayernorm_kernel(const float* __restrict__ x, const void* __restrict__ g,
                       size_t goff, const void* __restrict__ b, size_t boff,
                       float* __restrict__ out, const int* __restrict__ flg) {
    int isb = flg[0];
    int row = blockIdx.x;
    int tid = threadIdx.x;
    const float* xr = x + (size_t)row * CD;
    __shared__ float red[256];
    __shared__ float red2[256];
    int j0 = tid, j1 = tid + 256;
    float v0 = xr[1 + j0];
    float v1 = (j1 < CDS) ? xr[1 + j1] : 0.0f;
    red[tid]  = v0 + v1;
    red2[tid] = v0 * v0 + v1 * v1;
    __syncthreads();
    for (int off = 128; off > 0; off >>= 1) {
        if (tid < off) { red[tid] += red[tid + off]; red2[tid] += red2[tid + off]; }
        __syncthreads();
    }
    float mu  = red[0] * (1.0f / 383.0f);
    float var = red2[0] * (1.0f / 383.0f) - mu * mu;
    __syncthreads();
    float rstd = rsqrtf(var + 1e-5f);
    float y0 = (v0 - mu) * rstd * ldin(g, goff + j0, isb) + ldin(b, boff + j0, isb);
    float y1 = 0.0f;
    if (j1 < CDS) y1 = (v1 - mu) * rstd * ldin(g, goff + j1, isb) + ldin(b, boff + j1, isb);
    red[tid] = y0 * y0 + y1 * y1;
    __syncthreads();
    for (int off = 128; off > 0; off >>= 1) {
        if (tid < off) red[tid] += red[tid + off];
        __syncthreads();
    }
    float t = sqrtf(1.0f + red[0]);
    float* orow = out + (size_t)row * CD;
    orow[1 + j0] = y0;
    if (j1 < CDS) orow[1 + j1] = y1;
    if (tid == 0) orow[0] = t;
}

// ---------------------------------------------------------------------------
// lresnet: out = lnormalize(x + scale*y)
// ---------------------------------------------------------------------------
__global__ __launch_bounds__(256)
void lresnet_kernel(const float* __restrict__ x, const float* __restrict__ y,
                    float scale, float* __restrict__ out) {
    int row = blockIdx.x;
    int tid = threadIdx.x;
    const float* xr = x + (size_t)row * CD;
    const float* yr = y + (size_t)row * CD;
    __shared__ float red[256];
    float z0 = xr[tid] + scale * yr[tid];
    float z1 = 0.0f;
    float c = (tid == 0) ? z0 * z0 : -z0 * z0;
    if (tid < 128) { z1 = xr[256 + tid] + scale * yr[256 + tid]; c -= z1 * z1; }
    red[tid] = c;
    __syncthreads();
    for (int off = 128; off > 0; off >>= 1) {
        if (tid < off) red[tid] += red[tid + off];
        __syncthreads();
    }
    float rd = 1.0f / sqrtf(fmaxf(red[0], 1e-8f));
    float* orow = out + (size_t)row * CD;
    orow[tid] = z0 * rd;
    if (tid < 128) orow[256 + tid] = z1 * rd;
}

// lresnet vs broadcast dual-dtype pe (scale = 1)
__global__ __launch_bounds__(256)
void lresnet_pe_kernel(const float* __restrict__ x, const void* __restrict__ pe,
                       float* __restrict__ out, const int* __restrict__ flg) {
    int isb = flg[0];
    int row = blockIdx.x;
    int tid = threadIdx.x;
    const float* xr = x + (size_t)row * CD;
    size_t pb = (size_t)(row & (CN - 1)) * CD;
    __shared__ float red[256];
    float z0 = xr[tid] + ldin(pe, pb + tid, isb);
    float z1 = 0.0f;
    float c = (tid == 0) ? z0 * z0 : -z0 * z0;
    if (tid < 128) { z1 = xr[256 + tid] + ldin(pe, pb + 256 + tid, isb); c -= z1 * z1; }
    red[tid] = c;
    __syncthreads();
    for (int off = 128; off > 0; off >>= 1) {
        if (tid < off) red[tid] += red[tid + off];
        __syncthreads();
    }
    float rd = 1.0f / sqrtf(fmaxf(red[0], 1e-8f));
    float* orow = out + (size_t)row * CD;
    orow[tid] = z0 * rd;
    if (tid < 128) orow[256 + tid] = z1 * rd;
}

// ---------------------------------------------------------------------------
// qkv finish: src[8192,378] -> dst[B,H,N,64] with add_time.
// ---------------------------------------------------------------------------
__global__ __launch_bounds__(64)
void qkv_finish_kernel(const float* __restrict__ src, float* __restrict__ dst) {
    int row = blockIdx.x;
    int h   = blockIdx.y;
    int e   = threadIdx.x;
    float y = (e < CHCS) ? src[(size_t)row * CQN + h * CHCS + e] : 0.0f;
    float ss = y * y;
    #pragma unroll
    for (int off = 32; off > 0; off >>= 1) ss += __shfl_down(ss, off);
    float t = sqrtf(1.0f + __shfl(ss, 0));
    int b = row >> 8, n = row & 255;
    float* dr = dst + (((size_t)(b * CH + h)) * CN + n) * CHC;
    if (e < CHCS) dr[1 + e] = y;
    if (e == 0)   dr[0] = t;
}

// ---------------------------------------------------------------------------
// Attention v2: block = (query-chunk qc of 64, b*H+h). 256 thr.
// K staged bf16-transposed in LDS (conflict-free); V read coalesced from L2.
// grid (4, B*H).
// ---------------------------------------------------------------------------
__global__ __launch_bounds__(256)
void attn_kernel(const float* __restrict__ q, const float* __restrict__ k,
                 const float* __restrict__ v, float* __restrict__ attcat) {
    int qc = blockIdx.x;
    int bh = blockIdx.y;
    int h = bh % CH, b = bh / CH;
    int tid = threadIdx.x, wave = tid >> 6, lane = tid & 63;
    __shared__ unsigned short Kt[64][256];         // 32KB bf16 [c][m]
    __shared__ __align__(16) float esT[256][4];    // 4KB  scores/probs [m][qi]
    __shared__ float pvp[4][4][64];                // 4KB  [mchunk][qi][c]
    __shared__ float rs[4];
    const float* kb = k + (size_t)bh * CN * CHC;
    const float* vb = v + (size_t)bh * CN * CHC;
    // stage K transposed
    for (int i = tid; i < 4096; i += 256) {
        int cq = i >> 8, m = i & 255;
        float4 t = *(const float4*)(kb + (size_t)m * CHC + cq * 4);
        Kt[cq * 4 + 0][m] = f2bf(t.x);
        Kt[cq * 4 + 1][m] = f2bf(t.y);
        Kt[cq * 4 + 2][m] = f2bf(t.z);
        Kt[cq * 4 + 3][m] = f2bf(t.w);
    }
    __syncthreads();
    for (int g = 0; g < 16; g++) {
        int q0 = qc * 64 + g * 4;
        // lane c holds q[q0+qi][c] in regs (per wave)
        float q4[4];
        #pragma unroll
        for (int qi = 0; qi < 4; qi++)
            q4[qi] = q[((size_t)bh * CN + q0 + qi) * CHC + lane];
        // scores for m = tid (4 queries)
        {
            int m = tid;
            float s0, s1, s2, s3;
            float kc = bf2f(Kt[0][m]);
            s0 = -__shfl(q4[0], 0) * kc;
            s1 = -__shfl(q4[1], 0) * kc;
            s2 = -__shfl(q4[2], 0) * kc;
            s3 = -__shfl(q4[3], 0) * kc;
            #pragma unroll 4
            for (int c = 1; c < 64; c++) {
                float kcc = bf2f(Kt[c][m]);
                s0 += __shfl(q4[0], c) * kcc;
                s1 += __shfl(q4[1], c) * kcc;
                s2 += __shfl(q4[2], c) * kcc;
                s3 += __shfl(q4[3], c) * kcc;
            }
            esT[m][0] = 0.25f + 0.25f * s0;
            esT[m][1] = 0.25f + 0.25f * s1;
            esT[m][2] = 0.25f + 0.25f * s2;
            esT[m][3] = 0.25f + 0.25f * s3;
        }
        __syncthreads();
        // softmax: wave w handles query w
        {
            float v0 = esT[lane][wave],       v1 = esT[lane + 64][wave],
                  v2 = esT[lane + 128][wave], v3 = esT[lane + 192][wave];
            float mx = fmaxf(fmaxf(v0, v1), fmaxf(v2, v3));
            #pragma unroll
            for (int off = 32; off > 0; off >>= 1) mx = fmaxf(mx, __shfl_xor(mx, off));
            v0 = __expf(v0 - mx); v1 = __expf(v1 - mx);
            v2 = __expf(v2 - mx); v3 = __expf(v3 - mx);
            float sm = v0 + v1 + v2 + v3;
            #pragma unroll
            for (int off = 32; off > 0; off >>= 1) sm += __shfl_xor(sm, off);
            esT[lane][wave] = v0; esT[lane + 64][wave] = v1;
            esT[lane + 128][wave] = v2; esT[lane + 192][wave] = v3;
            if (lane == 0) rs[wave] = 1.0f / sm;
        }
        __syncthreads();
        // PV: wave = m-chunk, lane = c; V from global (coalesced, L2-hot)
        {
            float a0 = 0, a1 = 0, a2 = 0, a3 = 0;
            const float* vp = vb + (size_t)wave * 64 * CHC + lane;
            int mbase = wave * 64;
            #pragma unroll 4
            for (int mm = 0; mm < 64; mm++) {
                float vv = vp[mm * CHC];
                float4 e4 = *(const float4*)&esT[mbase + mm][0];
                a0 += e4.x * vv; a1 += e4.y * vv; a2 += e4.z * vv; a3 += e4.w * vv;
            }
            pvp[wave][0][lane] = a0; pvp[wave][1][lane] = a1;
            pvp[wave][2][lane] = a2; pvp[wave][3][lane] = a3;
        }
        __syncthreads();
        // epilogue: wave = qi, lane = c; lnormalize + concat write
        {
            int qi = wave, c = lane;
            float a = (pvp[0][qi][c] + pvp[1][qi][c] + pvp[2][qi][c] + pvp[3][qi][c]) * rs[qi];
            float val = (c == 0) ? a * a : -a * a;
            #pragma unroll
            for (int off = 32; off > 0; off >>= 1) val += __shfl_xor(val, off);
            float d = sqrtf(fmaxf(val, 1e-8f));
            attcat[((size_t)b * CN + q0 + qi) * CD + h * CHC + c] = a / d;
        }
        __syncthreads();
    }
}

// ---------------------------------------------------------------------------
// mean-pool over tokens + lnormalize -> emb[32,384]
// ---------------------------------------------------------------------------
__global__ __launch_bounds__(256)
void meanpool_kernel(const float* __restrict__ hbuf, float* __restrict__ emb) {
    int b = blockIdx.x;
    int tid = threadIdx.x;
    const float* hb = hbuf + (size_t)b * CN * CD;
    float s0 = 0.0f, s1 = 0.0f;
    for (int n = 0; n < CN; n++) {
        s0 += hb[(size_t)n * CD + tid];
        if (tid < 128) s1 += hb[(size_t)n * CD + 256 + tid];
    }
    s0 *= (1.0f / 256.0f);
    s1 *= (1.0f / 256.0f);
    __shared__ float red[256];
    float c = (tid == 0) ? s0 * s0 : -s0 * s0;
    if (tid < 128) c -= s1 * s1;
    red[tid] = c;
    __syncthreads();
    for (int off = 128; off > 0; off >>= 1) {
        if (tid < off) red[tid] += red[tid + off];
        __syncthreads();
    }
    float rd = 1.0f / sqrtf(fmaxf(red[0], 1e-8f));
    emb[(size_t)b * CD + tid] = s0 * rd;
    if (tid < 128) emb[(size_t)b * CD + 256 + tid] = s1 * rd;
}

// ---------------------------------------------------------------------------
// MLR head precompute + logits
// ---------------------------------------------------------------------------
__global__ __launch_bounds__(256)
void head_pre_kernel(const void* __restrict__ mlra, const void* __restrict__ mlrz,
                     float* __restrict__ wt, float* __restrict__ beta,
                     float* __restrict__ cha, const int* __restrict__ flg) {
    int isb = flg[0];
    int c = blockIdx.x * 256 + threadIdx.x;
    if (c >= 1000) return;
    float S = 0.0f;
    for (int j = 0; j < CDS; j++) {
        float zz = ldin(mlrz, (size_t)c * CDS + j, isb);
        S += zz * zz;
    }
    float a  = ldin(mlra, c, isb);
    float sh = sinhf(a), ch = coshf(a);
    float zn = sqrtf(S + 1e-8f);
    float w  = sh * zn;
    wt[c]  = w;
    cha[c] = ch;
    beta[c] = sqrtf(fmaxf(ch * ch * S - w * w, 1e-8f));
}

__global__ __launch_bounds__(256)
void head_logits_kernel(const float* __restrict__ emb, const void* __restrict__ mlrz,
                        const float* __restrict__ wt, const float* __restrict__ beta,
                        const float* __restrict__ cha, void* __restrict__ out,
                        const int* __restrict__ flg) {
    int isb = flg[0];
    int b = blockIdx.x;
    int c = blockIdx.y * 256 + threadIdx.x;
    __shared__ float es[CD];
    for (int j = threadIdx.x; j < CD; j += 256) es[j] = emb[(size_t)b * CD + j];
    __syncthreads();
    if (c < 1000) {
        float dotv = 0.0f;
        for (int j = 0; j < CDS; j++)
            dotv += es[1 + j] * ldin(mlrz, (size_t)c * CDS + j, isb);
        float alpha = -es[0] * wt[c] + cha[c] * dotv;
        float be = beta[c];
        float lg = be * asinhf(alpha / be);
        if (isb) ((bf16*)out)[(size_t)b * 1000 + c] = __float2bfloat16(lg);
        else     ((float*)out)[(size_t)b * 1000 + c] = lg;
    }
}

// ---------------------------------------------------------------------------
// Orchestration (workspace layout unchanged from round 3/4).
// ---------------------------------------------------------------------------
extern "C" void kernel_launch(void* const* d_in, const int* in_sizes, int n_in,
                              void* d_out, int out_size, void* d_ws, size_t ws_size,
                              hipStream_t stream) {
    const void* x      = d_in[0];
    const void* patchW = d_in[1];
    const void* patchB = d_in[2];
    const void* pe     = d_in[3];
    const void* ln1g   = d_in[4];
    const void* ln1b   = d_in[5];
    const void* ln2g   = d_in[6];
    const void* ln2b   = d_in[7];
    const void* Wq     = d_in[8];
    const void* bq     = d_in[9];
    const void* Wk     = d_in[10];
    const void* bk     = d_in[11];
    const void* Wv     = d_in[12];
    const void* bv     = d_in[13];
    const void* Wo     = d_in[14];
    const void* bo     = d_in[15];
    const void* W1     = d_in[16];
    const void* b1     = d_in[17];
    const void* W2     = d_in[18];
    const void* b2     = d_in[19];
    const void* mlra   = d_in[20];
    const void* mlrz   = d_in[21];

    float* ws = (float*)d_ws;
    const size_t FH = (size_t)CROWS * CD;
    float* hbuf   = ws;
    float* xln    = ws + FH;
    float* big1   = ws + 2 * FH;
    float* big2   = ws + 6 * FH;
    float* qb     = big2;
    float* kb     = big2 + FH;
    float* vb     = big2 + 2 * FH;
    float* attcat = big2 + 3 * FH;
    float* attout = big2;
    float* emb    = ws + 10 * FH;
    float* wt     = emb + (size_t)CB * CD;
    float* beta   = wt + 1000;
    float* cha    = beta + 1000;
    int*   flag   = (int*)(cha + 1000);

    const size_t WQKV = (size_t)CH * CD * CHCS;

    detect_kernel<<<1, 256, 0, stream>>>(x, flag);

    // patch embed
    patchify_kernel<<<cdiv(CB * 224 * 224, 256), 256, 0, stream>>>(x, big1, flag);
    gemm_kernel<<<dim3(cdiv(CDS, 64), CROWS / 64), 256, 0, stream>>>(
        big1, patchW, 0, patchB, 0, big2, CDS, CKP, 0, flag);
    add_time_rows_kernel<<<CROWS, 256, 0, stream>>>(big2, xln, CDS, 0);
    lresnet_pe_kernel<<<CROWS, 256, 0, stream>>>(xln, pe, hbuf, flag);

    for (int l = 0; l < CL; l++) {
        // --- attention block (residual base = LN1 output xln) ---
        llayernorm_kernel<<<CROWS, 256, 0, stream>>>(
            hbuf, ln1g, (size_t)l * CDS, ln1b, (size_t)l * CDS, xln, flag);
        gemm_kernel<<<dim3(cdiv(CQN, 64), CROWS / 64), 256, 0, stream>>>(
            xln, Wq, (size_t)l * WQKV, bq, (size_t)l * CQN, big1, CQN, CD, 1, flag);
        qkv_finish_kernel<<<dim3(CROWS, CH), 64, 0, stream>>>(big1, qb);
        gemm_kernel<<<dim3(cdiv(CQN, 64), CROWS / 64), 256, 0, stream>>>(
            xln, Wk, (size_t)l * WQKV, bk, (size_t)l * CQN, big1, CQN, CD, 1, flag);
        qkv_finish_kernel<<<dim3(CROWS, CH), 64, 0, stream>>>(big1, kb);
        gemm_kernel<<<dim3(cdiv(CQN, 64), CROWS / 64), 256, 0, stream>>>(
            xln, Wv, (size_t)l * WQKV, bv, (size_t)l * CQN, big1, CQN, CD, 1, flag);
        qkv_finish_kernel<<<dim3(CROWS, CH), 64, 0, stream>>>(big1, vb);
        attn_kernel<<<dim3(4, CB * CH), 256, 0, stream>>>(qb, kb, vb, attcat);
        gemm_kernel<<<dim3(cdiv(CDS, 64), CROWS / 64), 256, 0, stream>>>(
            attcat, Wo, (size_t)l * CD * CDS, bo, (size_t)l * CDS, big1, CDS, CD, 0, flag);
        add_time_rows_kernel<<<CROWS, 256, 0, stream>>>(big1, attout, CDS, 0);
        lresnet_kernel<<<CROWS, 256, 0, stream>>>(xln, attout, 27.5f, hbuf);
        // --- mlp block (residual base = hbuf) ---
        llayernorm_kernel<<<CROWS, 256, 0, stream>>>(
            hbuf, ln2g, (size_t)l * CDS, ln2b, (size_t)l * CDS, xln, flag);
        gemm_kernel<<<dim3(cdiv(CMHS, 64), CROWS / 64), 256, 0, stream>>>(
            xln, W1, (size_t)l * CD * CMHS, b1, (size_t)l * CMHS, big1, CMHS, CD, 0, flag);
        add_time_rows_kernel<<<CROWS, 256, 0, stream>>>(big1, big2, CMHS, 1);
        gemm_kernel<<<dim3(cdiv(CDS, 64), CROWS / 64), 256, 0, stream>>>(
            big2, W2, (size_t)l * CMH * CDS, b2, (size_t)l * CDS, big1, CDS, CMH, 0, flag);
        add_time_rows_kernel<<<CROWS, 256, 0, stream>>>(big1, xln, CDS, 0);
        lresnet_kernel<<<CROWS, 256, 0, stream>>>(hbuf, xln, 27.5f, hbuf);
    }

    // head
    meanpool_kernel<<<CB, 256, 0, stream>>>(hbuf, emb);
    head_pre_kernel<<<4, 256, 0, stream>>>(mlra, mlrz, wt, beta, cha, flag);
    head_logits_kernel<<<dim3(CB, 4), 256, 0, stream>>>(emb, mlrz, wt, beta, cha, d_out, flag);
}

// Round 7
// 5249.614 us; speedup vs baseline: 2.8097x; 1.3957x over previous
//
#include <hip/hip_runtime.h>
#include <hip/hip_bf16.h>
#include <math.h>

typedef __hip_bfloat16 bf16;

// Problem constants
constexpr int CB   = 32;    // batch
constexpr int CN   = 256;   // tokens
constexpr int CD   = 384;   // model dim (incl. time)
constexpr int CDS  = 383;   // space dim
constexpr int CH   = 6;     // heads
constexpr int CHC  = 64;    // head channels (incl. time)
constexpr int CHCS = 63;    // head space channels
constexpr int CL   = 12;    // layers
constexpr int CMH  = 1536;  // mlp hidden (incl. time)
constexpr int CMHS = 1535;
constexpr int CROWS = CB * CN;        // 8192
constexpr int CKP  = 784;             // patch vector length (14*14*4)
constexpr int CQN  = CH * CHCS;       // 378 (packed qkv out cols)

static inline int cdiv(int a, int b){ return (a + b - 1) / b; }

// MFMA frag types
typedef short bf8_t __attribute__((ext_vector_type(8)));
typedef float f4_t  __attribute__((ext_vector_type(4)));

// fp32 -> bf16 (RNE) raw
__device__ __forceinline__ unsigned short f2bf(float f) {
    union { float f; unsigned u; } x; x.f = f;
    unsigned r = x.u + 0x7FFFu + ((x.u >> 16) & 1u);
    return (unsigned short)(r >> 16);
}
__device__ __forceinline__ float bf2f(unsigned short h) {
    union { unsigned u; float f; } x; x.u = ((unsigned)h) << 16;
    return x.f;
}

// Dual-dtype input load: isb=1 -> bf16, isb=0 -> fp32. Wave-uniform isb.
__device__ __forceinline__ float ldin(const void* p, size_t i, int isb) {
    if (isb) return __bfloat162float(((const bf16*)p)[i]);
    return ((const float*)p)[i];
}

// ---------------------------------------------------------------------------
// Dtype detector (inputs fp32 expected; bf16 fallback).
// ---------------------------------------------------------------------------
__global__ __launch_bounds__(256)
void detect_kernel(const void* __restrict__ x, int* __restrict__ flag) {
    __shared__ int red[256];
    const unsigned short* u = (const unsigned short*)x;
    int cnt = 0;
    for (int i = threadIdx.x; i < 4096; i += 256) {
        unsigned short v = u[i];
        int e = (v >> 7) & 0xFF;
        cnt += (v == 0 || (e >= 96 && e <= 142)) ? 1 : 0;
    }
    red[threadIdx.x] = cnt;
    __syncthreads();
    for (int off = 128; off > 0; off >>= 1) {
        if (threadIdx.x < off) red[threadIdx.x] += red[threadIdx.x + off];
        __syncthreads();
    }
    if (threadIdx.x == 0) flag[0] = (red[0] >= 3482) ? 1 : 0;
}

// ---------------------------------------------------------------------------
// Patchify: x[B,3,224,224] -> patches[8192,784] fp32 with add_time per px
// ---------------------------------------------------------------------------
__global__ __launch_bounds__(256)
void patchify_kernel(const void* __restrict__ x, float* __restrict__ patches,
                     const int* __restrict__ flg) {
    int isb = flg[0];
    int idx = blockIdx.x * 256 + threadIdx.x;
    if (idx >= CB * 224 * 224) return;
    int col = idx % 224;
    int t   = idx / 224;
    int row = t % 224;
    int b   = t / 224;
    size_t base = ((size_t)b * 3) * 224 * 224 + (size_t)row * 224 + col;
    float r  = ldin(x, base, isb);
    float g  = ldin(x, base + 224 * 224, isb);
    float bl = ldin(x, base + 2 * 224 * 224, isb);
    float tt = sqrtf(1.0f + r * r + g * g + bl * bl);
    int gi = row / 14, pi = row % 14, gj = col / 14, pj = col % 14;
    int p = gi * 16 + gj;
    float* dp = patches + ((size_t)(b * CN + p)) * CKP + (pi * 14 + pj) * 4;
    *(float4*)dp = make_float4(tt, r, g, bl);
}

// ---------------------------------------------------------------------------
// MFMA GEMM: C[M,N] = A[M,K] @ W[K,N] + bias[N]. 64x64 tile, BK=32.
// ---------------------------------------------------------------------------
__global__ __launch_bounds__(256)
void gemm_kernel(const float* __restrict__ A, const void* __restrict__ W,
                 size_t woff, const void* __restrict__ bias, size_t boff,
                 float* __restrict__ C, int N, int K, int wmode,
                 const int* __restrict__ flg) {
    int isb = flg[0];
    __shared__ __align__(16) short Ablk[4][64][8];
    __shared__ __align__(16) short Bblk[4][64][8];
    int tid = threadIdx.x;
    int wave = tid >> 6, lane = tid & 63;
    int bm = blockIdx.y * 64, bn = blockIdx.x * 64;
    int wm = (wave & 1) * 2, wn = (wave >> 1) * 2;
    f4_t acc[2][2] = {};

    int mA = tid >> 2, kqA = tid & 3;
    const float* arow = A + (size_t)(bm + mA) * K;
    int nl = tid & 63;
    int nB = bn + nl;
    int kqB = tid >> 6;
    bool nval = nB < N;
    int ncl = nval ? nB : 0;
    size_t wcol; int wstr;
    if (wmode) { int h = ncl / 63, e = ncl % 63;
                 wcol = woff + (size_t)h * CD * 63 + e; wstr = 63; }
    else       { wcol = woff + ncl; wstr = N; }
    short* awp = &Ablk[mA >> 4][(mA & 15) | (kqA << 4)][0];
    short* bwp = &Bblk[nl >> 4][(nl & 15) | (kqB << 4)][0];

    for (int k0 = 0; k0 < K; k0 += 32) {
        {
            bf8_t av = {0,0,0,0,0,0,0,0};
            int kk = k0 + kqA * 8;
            if (kk < K) {
                float4 f0 = *(const float4*)(arow + kk);
                float4 f1 = *(const float4*)(arow + kk + 4);
                av[0]=(short)f2bf(f0.x); av[1]=(short)f2bf(f0.y);
                av[2]=(short)f2bf(f0.z); av[3]=(short)f2bf(f0.w);
                av[4]=(short)f2bf(f1.x); av[5]=(short)f2bf(f1.y);
                av[6]=(short)f2bf(f1.z); av[7]=(short)f2bf(f1.w);
            }
            *(bf8_t*)awp = av;
        }
        {
            bf8_t bv = {0,0,0,0,0,0,0,0};
            #pragma unroll
            for (int jj = 0; jj < 8; jj++) {
                int kr = k0 + kqB * 8 + jj;
                float wv = 0.0f;
                if (nval && kr < K) wv = ldin(W, wcol + (size_t)kr * wstr, isb);
                bv[jj] = (short)f2bf(wv);
            }
            *(bf8_t*)bwp = bv;
        }
        __syncthreads();
        bf8_t a0 = *(const bf8_t*)&Ablk[wm    ][lane][0];
        bf8_t a1 = *(const bf8_t*)&Ablk[wm + 1][lane][0];
        bf8_t b0 = *(const bf8_t*)&Bblk[wn    ][lane][0];
        bf8_t b1 = *(const bf8_t*)&Bblk[wn + 1][lane][0];
        acc[0][0] = __builtin_amdgcn_mfma_f32_16x16x32_bf16(a0, b0, acc[0][0], 0, 0, 0);
        acc[0][1] = __builtin_amdgcn_mfma_f32_16x16x32_bf16(a0, b1, acc[0][1], 0, 0, 0);
        acc[1][0] = __builtin_amdgcn_mfma_f32_16x16x32_bf16(a1, b0, acc[1][0], 0, 0, 0);
        acc[1][1] = __builtin_amdgcn_mfma_f32_16x16x32_bf16(a1, b1, acc[1][1], 0, 0, 0);
        __syncthreads();
    }
    int colq = lane & 15, rowq = (lane >> 4) * 4;
    #pragma unroll
    for (int ni = 0; ni < 2; ni++) {
        int col = bn + (wn + ni) * 16 + colq;
        if (col >= N) continue;
        float bb = ldin(bias, boff + col, isb);
        #pragma unroll
        for (int mi = 0; mi < 2; mi++) {
            int row = bm + (wm + mi) * 16 + rowq;
            #pragma unroll
            for (int r = 0; r < 4; r++)
                C[(size_t)(row + r) * N + col] = acc[mi][ni][r] + bb;
        }
    }
}

// ---------------------------------------------------------------------------
// add_time rows (+optional GELU). src [M,NS], dst [M,NS+1].
// ---------------------------------------------------------------------------
__global__ __launch_bounds__(256)
void add_time_rows_kernel(const float* __restrict__ src, float* __restrict__ dst,
                          int NS, int do_gelu) {
    int row = blockIdx.x;
    int tid = threadIdx.x;
    __shared__ float buf[1536];
    __shared__ float red[256];
    const float* sr = src + (size_t)row * NS;
    float ss = 0.0f;
    for (int j = tid; j < NS; j += 256) {
        float vv = sr[j];
        if (do_gelu) {
            float x3 = vv * vv * vv;
            vv = 0.5f * vv * (1.0f + tanhf(0.7978845608028654f * (vv + 0.044715f * x3)));
        }
        buf[j] = vv;
        ss += vv * vv;
    }
    red[tid] = ss;
    __syncthreads();
    for (int off = 128; off > 0; off >>= 1) {
        if (tid < off) red[tid] += red[tid + off];
        __syncthreads();
    }
    float t = sqrtf(1.0f + red[0]);
    float* dr = dst + (size_t)row * (NS + 1);
    if (tid == 0) dr[0] = t;
    for (int j = tid; j < NS; j += 256) dr[1 + j] = buf[j];
}

// ---------------------------------------------------------------------------
// Fused: out = lnormalize(base + scale * add_time(src)); src [M,383] raw gemm
// out, base/out [M,384]. In-place safe when base == out (row-local).
// ---------------------------------------------------------------------------
__global__ __launch_bounds__(256)
void addtime_lresnet_kernel(const float* __restrict__ src,
                            const float* __restrict__ base, float scale,
                            float* __restrict__ out) {
    int row = blockIdx.x;
    int tid = threadIdx.x;
    const float* sr = src + (size_t)row * CDS;
    const float* br = base + (size_t)row * CD;
    __shared__ float red[256];
    float s0 = (tid > 0) ? sr[tid - 1] : 0.0f;
    float s1 = (tid < 128) ? sr[tid + 255] : 0.0f;
    red[tid] = s0 * s0 + s1 * s1;
    __syncthreads();
    for (int off = 128; off > 0; off >>= 1) {
        if (tid < off) red[tid] += red[tid + off];
        __syncthreads();
    }
    float t = sqrtf(1.0f + red[0]);
    __syncthreads();
    float y0 = (tid == 0) ? t : s0;
    float z0 = br[tid] + scale * y0;
    float z1 = (tid < 128) ? br[tid + 256] + scale * s1 : 0.0f;
    float c = (tid == 0) ? z0 * z0 : -z0 * z0;
    c -= z1 * z1;
    red[tid] = c;
    __syncthreads();
    for (int off = 128; off > 0; off >>= 1) {
        if (tid < off) red[tid] += red[tid + off];
        __syncthreads();
    }
    float rd = 1.0f / sqrtf(fmaxf(red[0], 1e-8f));
    float* orow = out + (size_t)row * CD;
    orow[tid] = z0 * rd;
    if (tid < 128) orow[256 + tid] = z1 * rd;
}

// ---------------------------------------------------------------------------
// Lorentz layernorm: x[M,384] -> out[M,384]
// ---------------------------------------------------------------------------
__global__ __launch_bounds__(256)
void llayernorm_kernel(const float* __restrict__ x, const void* __restrict__ g,
                       size_t goff, const void* __restrict__ b, size_t boff,
                       float* __restrict__ out, const int* __restrict__ flg) {
    int isb = flg[0];
    int row = blockIdx.x;
    int tid = threadIdx.x;
    const float* xr = x + (size_t)row * CD;
    __shared__ float red[256];
    __shared__ float red2[256];
    int j0 = tid, j1 = tid + 256;
    float v0 = xr[1 + j0];
    float v1 = (j1 < CDS) ? xr[1 + j1] : 0.0f;
    red[tid]  = v0 + v1;
    red2[tid] = v0 * v0 + v1 * v1;
    __syncthreads();
    for (int off = 128; off > 0; off >>= 1) {
        if (tid < off) { red[tid] += red[tid + off]; red2[tid] += red2[tid + off]; }
        __syncthreads();
    }
    float mu  = red[0] * (1.0f / 383.0f);
    float var = red2[0] * (1.0f / 383.0f) - mu * mu;
    __syncthreads();
    float rstd = rsqrtf(var + 1e-5f);
    float y0 = (v0 - mu) * rstd * ldin(g, goff + j0, isb) + ldin(b, boff + j0, isb);
    float y1 = 0.0f;
    if (j1 < CDS) y1 = (v1 - mu) * rstd * ldin(g, goff + j1, isb) + ldin(b, boff + j1, isb);
    red[tid] = y0 * y0 + y1 * y1;
    __syncthreads();
    for (int off = 128; off > 0; off >>= 1) {
        if (tid < off) red[tid] += red[tid + off];
        __syncthreads();
    }
    float t = sqrtf(1.0f + red[0]);
    float* orow = out + (size_t)row * CD;
    orow[1 + j0] = y0;
    if (j1 < CDS) orow[1 + j1] = y1;
    if (tid == 0) orow[0] = t;
}

// lresnet vs broadcast dual-dtype pe (scale = 1)
__global__ __launch_bounds__(256)
void lresnet_pe_kernel(const float* __restrict__ x, const void* __restrict__ pe,
                       float* __restrict__ out, const int* __restrict__ flg) {
    int isb = flg[0];
    int row = blockIdx.x;
    int tid = threadIdx.x;
    const float* xr = x + (size_t)row * CD;
    size_t pb = (size_t)(row & (CN - 1)) * CD;
    __shared__ float red[256];
    float z0 = xr[tid] + ldin(pe, pb + tid, isb);
    float z1 = 0.0f;
    float c = (tid == 0) ? z0 * z0 : -z0 * z0;
    if (tid < 128) { z1 = xr[256 + tid] + ldin(pe, pb + 256 + tid, isb); c -= z1 * z1; }
    red[tid] = c;
    __syncthreads();
    for (int off = 128; off > 0; off >>= 1) {
        if (tid < off) red[tid] += red[tid + off];
        __syncthreads();
    }
    float rd = 1.0f / sqrtf(fmaxf(red[0], 1e-8f));
    float* orow = out + (size_t)row * CD;
    orow[tid] = z0 * rd;
    if (tid < 128) orow[256 + tid] = z1 * rd;
}

// ---------------------------------------------------------------------------
// qkv finish: src[8192,378] -> dst[B,H,N,64] with add_time.
// ---------------------------------------------------------------------------
__global__ __launch_bounds__(64)
void qkv_finish_kernel(const float* __restrict__ src, float* __restrict__ dst) {
    int row = blockIdx.x;
    int h   = blockIdx.y;
    int e   = threadIdx.x;
    float y = (e < CHCS) ? src[(size_t)row * CQN + h * CHCS + e] : 0.0f;
    float ss = y * y;
    #pragma unroll
    for (int off = 32; off > 0; off >>= 1) ss += __shfl_down(ss, off);
    float t = sqrtf(1.0f + __shfl(ss, 0));
    int b = row >> 8, n = row & 255;
    float* dr = dst + (((size_t)(b * CH + h)) * CN + n) * CHC;
    if (e < CHCS) dr[1 + e] = y;
    if (e == 0)   dr[0] = t;
}

// ---------------------------------------------------------------------------
// Attention v4 (MFMA, split-precision): block = (64 queries, bh). 256 thr.
// Scores: (Qhi+Qlo)·K  (Q split -> ~fp32-exact Q, K bf16 = round-5 class).
// PV: O = Phi·Vhi + Plo·Vhi + Phi·Vlo  (~fp32 precision), three LDS passes
// reusing the same 64 KB (Pf rewrites are wave-local; Bv restaged from L2).
// grid (4, B*H).
// ---------------------------------------------------------------------------
__global__ __launch_bounds__(256)
void attn_kernel(const float* __restrict__ q, const float* __restrict__ k,
                 const float* __restrict__ v, float* __restrict__ attcat) {
    __shared__ __align__(16) unsigned char smem[65536];
    unsigned short* Aqh = (unsigned short*)smem;             // 8KB [4][2][64][8]
    unsigned short* Aql = (unsigned short*)(smem + 8192);    // 8KB
    unsigned short* Bk  = (unsigned short*)(smem + 16384);   // 32KB [16][2][64][8]
    unsigned short* Pf  = (unsigned short*)smem;             // 32KB [4][8][64][8]
    unsigned short* Bv  = (unsigned short*)(smem + 32768);   // 32KB [4][8][64][8]
    int qc = blockIdx.x, bh = blockIdx.y;
    int h = bh % CH, b = bh / CH;
    int tid = threadIdx.x, wave = tid >> 6, lane = tid & 63;
    const float* qb = q + ((size_t)bh * CN + qc * 64) * CHC;
    const float* kb = k + (size_t)bh * CN * CHC;
    const float* vb = v + (size_t)bh * CN * CHC;

    // stage Q' hi/lo -> A-frag (negate time channel before split)
    #pragma unroll
    for (int it = 0; it < 4; it++) {
        int flat = it * 256 + tid;
        int ql = flat >> 4;
        int c4 = (flat & 15) * 4;
        float4 f = *(const float4*)(qb + ql * CHC + c4);
        if (c4 == 0) f.x = -f.x;
        int mt = ql >> 4, ks = c4 >> 5;
        int lp = (ql & 15) | (((c4 >> 3) & 3) << 4);
        int off = (((mt * 2 + ks) * 64 + lp) * 8) + (c4 & 7);
        float fv[4] = {f.x, f.y, f.z, f.w};
        #pragma unroll
        for (int i = 0; i < 4; i++) {
            unsigned short hi = f2bf(fv[i]);
            Aqh[off + i] = hi;
            Aql[off + i] = f2bf(fv[i] - bf2f(hi));
        }
    }
    // stage K -> B-frag (bf16)
    #pragma unroll
    for (int it = 0; it < 16; it++) {
        int flat = it * 256 + tid;
        int tk = flat >> 4;
        int c4 = (flat & 15) * 4;
        float4 f = *(const float4*)(kb + tk * CHC + c4);
        int nt = tk >> 4, ks = c4 >> 5;
        int lp = (tk & 15) | (((c4 >> 3) & 3) << 4);
        unsigned short* dst = Bk + (((nt * 2 + ks) * 64 + lp) * 8) + (c4 & 7);
        dst[0] = f2bf(f.x); dst[1] = f2bf(f.y); dst[2] = f2bf(f.z); dst[3] = f2bf(f.w);
    }
    __syncthreads();
    // S = Q'·K for this wave's 16 queries
    f4_t s[16];
    #pragma unroll
    for (int nt = 0; nt < 16; nt++) s[nt] = (f4_t){0.0f, 0.0f, 0.0f, 0.0f};
    bf8_t ah0 = *(const bf8_t*)(Aqh + ((wave * 2 + 0) * 64 + lane) * 8);
    bf8_t ah1 = *(const bf8_t*)(Aqh + ((wave * 2 + 1) * 64 + lane) * 8);
    bf8_t al0 = *(const bf8_t*)(Aql + ((wave * 2 + 0) * 64 + lane) * 8);
    bf8_t al1 = *(const bf8_t*)(Aql + ((wave * 2 + 1) * 64 + lane) * 8);
    #pragma unroll
    for (int nt = 0; nt < 16; nt++) {
        bf8_t b0 = *(const bf8_t*)(Bk + ((nt * 2 + 0) * 64 + lane) * 8);
        bf8_t b1 = *(const bf8_t*)(Bk + ((nt * 2 + 1) * 64 + lane) * 8);
        s[nt] = __builtin_amdgcn_mfma_f32_16x16x32_bf16(ah0, b0, s[nt], 0, 0, 0);
        s[nt] = __builtin_amdgcn_mfma_f32_16x16x32_bf16(ah1, b1, s[nt], 0, 0, 0);
        s[nt] = __builtin_amdgcn_mfma_f32_16x16x32_bf16(al0, b0, s[nt], 0, 0, 0);
        s[nt] = __builtin_amdgcn_mfma_f32_16x16x32_bf16(al1, b1, s[nt], 0, 0, 0);
    }
    // softmax per query row (row lives in one 16-lane quad)
    float mx[4] = {-1e30f, -1e30f, -1e30f, -1e30f};
    #pragma unroll
    for (int nt = 0; nt < 16; nt++)
        #pragma unroll
        for (int r = 0; r < 4; r++) mx[r] = fmaxf(mx[r], s[nt][r]);
    #pragma unroll
    for (int off = 1; off < 16; off <<= 1)
        #pragma unroll
        for (int r = 0; r < 4; r++) mx[r] = fmaxf(mx[r], __shfl_xor(mx[r], off));
    float sm[4] = {0.0f, 0.0f, 0.0f, 0.0f};
    #pragma unroll
    for (int nt = 0; nt < 16; nt++)
        #pragma unroll
        for (int r = 0; r < 4; r++) {
            float e = __expf(0.25f * (s[nt][r] - mx[r]));
            s[nt][r] = e; sm[r] += e;
        }
    #pragma unroll
    for (int off = 1; off < 16; off <<= 1)
        #pragma unroll
        for (int r = 0; r < 4; r++) sm[r] += __shfl_xor(sm[r], off);
    #pragma unroll
    for (int r = 0; r < 4; r++) sm[r] = 1.0f / sm[r];
    #pragma unroll
    for (int nt = 0; nt < 16; nt++)
        #pragma unroll
        for (int r = 0; r < 4; r++) s[nt][r] *= sm[r];   // s = normalized P (fp32)

    int colq = lane & 15, quad = lane >> 4;
    // helpers
    auto writePf = [&](int lo) {
        #pragma unroll
        for (int nt = 0; nt < 16; nt++) {
            int key = nt * 16 + colq;
            int ks = key >> 5;
            #pragma unroll
            for (int r = 0; r < 4; r++) {
                int qrow = quad * 4 + r;
                int lp = (qrow & 15) | (((key >> 3) & 3) << 4);
                float p = s[nt][r];
                unsigned short hi = f2bf(p);
                unsigned short w = lo ? f2bf(p - bf2f(hi)) : hi;
                Pf[((wave * 8 + ks) * 64 + lp) * 8 + (key & 7)] = w;
            }
        }
    };
    auto stageBv = [&](int lo) {
        #pragma unroll
        for (int it = 0; it < 16; it++) {
            int flat = it * 256 + tid;
            int tk = flat >> 4;
            int c4 = (flat & 15) * 4;
            float4 f = *(const float4*)(vb + tk * CHC + c4);
            int ks = tk >> 5, jj = tk & 7, kq = (tk >> 3) & 3;
            int nt = c4 >> 4;
            int lq = (c4 & 15) | (kq << 4);
            unsigned short* base = Bv + ((nt * 8 + ks) * 64) * 8 + jj;
            float fv[4] = {f.x, f.y, f.z, f.w};
            #pragma unroll
            for (int i = 0; i < 4; i++) {
                unsigned short hi = f2bf(fv[i]);
                base[(lq + i) * 8] = lo ? f2bf(fv[i] - bf2f(hi)) : hi;
            }
        }
    };
    f4_t o[4] = {};
    auto pvpass = [&]() {
        #pragma unroll
        for (int ks = 0; ks < 8; ks++) {
            bf8_t pa = *(const bf8_t*)(Pf + ((wave * 8 + ks) * 64 + lane) * 8);
            #pragma unroll
            for (int nt = 0; nt < 4; nt++) {
                bf8_t vv = *(const bf8_t*)(Bv + ((nt * 8 + ks) * 64 + lane) * 8);
                o[nt] = __builtin_amdgcn_mfma_f32_16x16x32_bf16(pa, vv, o[nt], 0, 0, 0);
            }
        }
    };

    __syncthreads();            // Aq/Bk fully consumed
    writePf(0); stageBv(0);
    __syncthreads();
    pvpass();                   // Phi·Vhi
    __syncthreads();
    writePf(1);                 // Pf rewrite (wave-local)
    __syncthreads();
    pvpass();                   // Plo·Vhi
    __syncthreads();
    writePf(0); stageBv(1);     // Bv -> V_lo (L2-hot re-read)
    __syncthreads();
    pvpass();                   // Phi·Vlo

    // lnormalize rows + write concat layout
    {
        float nrm[4] = {0.0f, 0.0f, 0.0f, 0.0f};
        #pragma unroll
        for (int nt = 0; nt < 4; nt++) {
            float sgn = (nt == 0 && colq == 0) ? 1.0f : -1.0f;
            #pragma unroll
            for (int r = 0; r < 4; r++) nrm[r] += sgn * o[nt][r] * o[nt][r];
        }
        #pragma unroll
        for (int off = 1; off < 16; off <<= 1)
            #pragma unroll
            for (int r = 0; r < 4; r++) nrm[r] += __shfl_xor(nrm[r], off);
        #pragma unroll
        for (int r = 0; r < 4; r++) {
            float d = 1.0f / sqrtf(fmaxf(nrm[r], 1e-8f));
            int qg = qc * 64 + wave * 16 + quad * 4 + r;
            float* orow = attcat + ((size_t)b * CN + qg) * CD + h * CHC;
            #pragma unroll
            for (int nt = 0; nt < 4; nt++)
                orow[nt * 16 + colq] = o[nt][r] * d;
        }
    }
}

// ---------------------------------------------------------------------------
// mean-pool over tokens + lnormalize -> emb[32,384]
// ---------------------------------------------------------------------------
__global__ __launch_bounds__(256)
void meanpool_kernel(const float* __restrict__ hbuf, float* __restrict__ emb) {
    int b = blockIdx.x;
    int tid = threadIdx.x;
    const float* hb = hbuf + (size_t)b * CN * CD;
    float s0 = 0.0f, s1 = 0.0f;
    for (int n = 0; n < CN; n++) {
        s0 += hb[(size_t)n * CD + tid];
        if (tid < 128) s1 += hb[(size_t)n * CD + 256 + tid];
    }
    s0 *= (1.0f / 256.0f);
    s1 *= (1.0f / 256.0f);
    __shared__ float red[256];
    float c = (tid == 0) ? s0 * s0 : -s0 * s0;
    if (tid < 128) c -= s1 * s1;
    red[tid] = c;
    __syncthreads();
    for (int off = 128; off > 0; off >>= 1) {
        if (tid < off) red[tid] += red[tid + off];
        __syncthreads();
    }
    float rd = 1.0f / sqrtf(fmaxf(red[0], 1e-8f));
    emb[(size_t)b * CD + tid] = s0 * rd;
    if (tid < 128) emb[(size_t)b * CD + 256 + tid] = s1 * rd;
}

// ---------------------------------------------------------------------------
// MLR head precompute + logits
// ---------------------------------------------------------------------------
__global__ __launch_bounds__(256)
void head_pre_kernel(const void* __restrict__ mlra, const void* __restrict__ mlrz,
                     float* __restrict__ wt, float* __restrict__ beta,
                     float* __restrict__ cha, const int* __restrict__ flg) {
    int isb = flg[0];
    int c = blockIdx.x * 256 + threadIdx.x;
    if (c >= 1000) return;
    float S = 0.0f;
    for (int j = 0; j < CDS; j++) {
        float zz = ldin(mlrz, (size_t)c * CDS + j, isb);
        S += zz * zz;
    }
    float a  = ldin(mlra, c, isb);
    float sh = sinhf(a), ch = coshf(a);
    float zn = sqrtf(S + 1e-8f);
    float w  = sh * zn;
    wt[c]  = w;
    cha[c] = ch;
    beta[c] = sqrtf(fmaxf(ch * ch * S - w * w, 1e-8f));
}

__global__ __launch_bounds__(256)
void head_logits_kernel(const float* __restrict__ emb, const void* __restrict__ mlrz,
                        const float* __restrict__ wt, const float* __restrict__ beta,
                        const float* __restrict__ cha, void* __restrict__ out,
                        const int* __restrict__ flg) {
    int isb = flg[0];
    int b = blockIdx.x;
    int c = blockIdx.y * 256 + threadIdx.x;
    __shared__ float es[CD];
    for (int j = threadIdx.x; j < CD; j += 256) es[j] = emb[(size_t)b * CD + j];
    __syncthreads();
    if (c < 1000) {
        float dotv = 0.0f;
        for (int j = 0; j < CDS; j++)
            dotv += es[1 + j] * ldin(mlrz, (size_t)c * CDS + j, isb);
        float alpha = -es[0] * wt[c] + cha[c] * dotv;
        float be = beta[c];
        float lg = be * asinhf(alpha / be);
        if (isb) ((bf16*)out)[(size_t)b * 1000 + c] = __float2bfloat16(lg);
        else     ((float*)out)[(size_t)b * 1000 + c] = lg;
    }
}

// ---------------------------------------------------------------------------
// Orchestration (workspace layout unchanged).
// ---------------------------------------------------------------------------
extern "C" void kernel_launch(void* const* d_in, const int* in_sizes, int n_in,
                              void* d_out, int out_size, void* d_ws, size_t ws_size,
                              hipStream_t stream) {
    const void* x      = d_in[0];
    const void* patchW = d_in[1];
    const void* patchB = d_in[2];
    const void* pe     = d_in[3];
    const void* ln1g   = d_in[4];
    const void* ln1b   = d_in[5];
    const void* ln2g   = d_in[6];
    const void* ln2b   = d_in[7];
    const void* Wq     = d_in[8];
    const void* bq     = d_in[9];
    const void* Wk     = d_in[10];
    const void* bk     = d_in[11];
    const void* Wv     = d_in[12];
    const void* bv     = d_in[13];
    const void* Wo     = d_in[14];
    const void* bo     = d_in[15];
    const void* W1     = d_in[16];
    const void* b1     = d_in[17];
    const void* W2     = d_in[18];
    const void* b2     = d_in[19];
    const void* mlra   = d_in[20];
    const void* mlrz   = d_in[21];

    float* ws = (float*)d_ws;
    const size_t FH = (size_t)CROWS * CD;
    float* hbuf   = ws;
    float* xln    = ws + FH;
    float* big1   = ws + 2 * FH;
    float* big2   = ws + 6 * FH;
    float* qb     = big2;
    float* kb     = big2 + FH;
    float* vb     = big2 + 2 * FH;
    float* attcat = big2 + 3 * FH;
    float* emb    = ws + 10 * FH;
    float* wt     = emb + (size_t)CB * CD;
    float* beta   = wt + 1000;
    float* cha    = beta + 1000;
    int*   flag   = (int*)(cha + 1000);

    const size_t WQKV = (size_t)CH * CD * CHCS;

    detect_kernel<<<1, 256, 0, stream>>>(x, flag);

    // patch embed
    patchify_kernel<<<cdiv(CB * 224 * 224, 256), 256, 0, stream>>>(x, big1, flag);
    gemm_kernel<<<dim3(cdiv(CDS, 64), CROWS / 64), 256, 0, stream>>>(
        big1, patchW, 0, patchB, 0, big2, CDS, CKP, 0, flag);
    add_time_rows_kernel<<<CROWS, 256, 0, stream>>>(big2, xln, CDS, 0);
    lresnet_pe_kernel<<<CROWS, 256, 0, stream>>>(xln, pe, hbuf, flag);

    for (int l = 0; l < CL; l++) {
        // --- attention block (residual base = LN1 output xln) ---
        llayernorm_kernel<<<CROWS, 256, 0, stream>>>(
            hbuf, ln1g, (size_t)l * CDS, ln1b, (size_t)l * CDS, xln, flag);
        gemm_kernel<<<dim3(cdiv(CQN, 64), CROWS / 64), 256, 0, stream>>>(
            xln, Wq, (size_t)l * WQKV, bq, (size_t)l * CQN, big1, CQN, CD, 1, flag);
        qkv_finish_kernel<<<dim3(CROWS, CH), 64, 0, stream>>>(big1, qb);
        gemm_kernel<<<dim3(cdiv(CQN, 64), CROWS / 64), 256, 0, stream>>>(
            xln, Wk, (size_t)l * WQKV, bk, (size_t)l * CQN, big1, CQN, CD, 1, flag);
        qkv_finish_kernel<<<dim3(CROWS, CH), 64, 0, stream>>>(big1, kb);
        gemm_kernel<<<dim3(cdiv(CQN, 64), CROWS / 64), 256, 0, stream>>>(
            xln, Wv, (size_t)l * WQKV, bv, (size_t)l * CQN, big1, CQN, CD, 1, flag);
        qkv_finish_kernel<<<dim3(CROWS, CH), 64, 0, stream>>>(big1, vb);
        attn_kernel<<<dim3(4, CB * CH), 256, 0, stream>>>(qb, kb, vb, attcat);
        gemm_kernel<<<dim3(cdiv(CDS, 64), CROWS / 64), 256, 0, stream>>>(
            attcat, Wo, (size_t)l * CD * CDS, bo, (size_t)l * CDS, big1, CDS, CD, 0, flag);
        addtime_lresnet_kernel<<<CROWS, 256, 0, stream>>>(big1, xln, 27.5f, hbuf);
        // --- mlp block (residual base = hbuf) ---
        llayernorm_kernel<<<CROWS, 256, 0, stream>>>(
            hbuf, ln2g, (size_t)l * CDS, ln2b, (size_t)l * CDS, xln, flag);
        gemm_kernel<<<dim3(cdiv(CMHS, 64), CROWS / 64), 256, 0, stream>>>(
            xln, W1, (size_t)l * CD * CMHS, b1, (size_t)l * CMHS, big1, CMHS, CD, 0, flag);
        add_time_rows_kernel<<<CROWS, 256, 0, stream>>>(big1, big2, CMHS, 1);
        gemm_kernel<<<dim3(cdiv(CDS, 64), CROWS / 64), 256, 0, stream>>>(
            big2, W2, (size_t)l * CMH * CDS, b2, (size_t)l * CDS, big1, CDS, CMH, 0, flag);
        addtime_lresnet_kernel<<<CROWS, 256, 0, stream>>>(big1, hbuf, 27.5f, hbuf);
    }

    // head
    meanpool_kernel<<<CB, 256, 0, stream>>>(hbuf, emb);
    head_pre_kernel<<<4, 256, 0, stream>>>(mlra, mlrz, wt, beta, cha, flag);
    head_logits_kernel<<<dim3(CB, 4), 256, 0, stream>>>(emb, mlrz, wt, beta, cha, d_out, flag);
}